// Round 1
// baseline (853.647 us; speedup 1.0000x reference)
//
#include <hip/hip_runtime.h>
#include <math.h>

// Problem constants: B=1, CQ=8, CV=64, H=W=D=64, fp32.
#define SQC 262144   // channel stride = 64*64*64
#define SH  4096     // h stride = 64*64
#define SW  64       // w stride

// ---------------------------------------------------------------------------
// K1: per-query softmax stats (m = max over 192 energies, rl = 1/sum(exp)).
// Block covers 4h x 4w, 16 waves; wave = one (h,w); lane = d.
// ---------------------------------------------------------------------------
__global__ __launch_bounds__(1024, 4) void k_stats(
    const float* __restrict__ Q, const float* __restrict__ K,
    float* __restrict__ m_ws, float* __restrict__ rl_ws)
{
    const int tid = threadIdx.x;
    const int d   = tid & 63;
    const int wid = tid >> 6;                 // 0..15
    const int hg = blockIdx.x >> 4, wg = blockIdx.x & 15;
    const int h = hg * 4 + (wid >> 2);
    const int w = wg * 4 + (wid & 3);

    float q[8];
#pragma unroll
    for (int c = 0; c < 8; ++c) q[c] = Q[c * SQC + h * SH + w * SW + d];

    float mH, lH, mW, lW, mD, lD;

    // ---- H axis: keys at (c, x, w, d), mask x==h ----
    {
        float e[64];
#pragma unroll
        for (int x = 0; x < 64; ++x) {
            float a = 0.f;
#pragma unroll
            for (int c = 0; c < 8; ++c)
                a = fmaf(q[c], K[c * SQC + x * SH + w * SW + d], a);
            e[x] = (x == h) ? -INFINITY : a;
        }
        float mm = -INFINITY;
#pragma unroll
        for (int x = 0; x < 64; ++x) mm = fmaxf(mm, e[x]);
        float ll = 0.f;
#pragma unroll
        for (int x = 0; x < 64; ++x) ll += __expf(e[x] - mm);
        mH = mm; lH = ll;
    }
    __syncthreads();   // keep waves loosely in step for L1 reuse

    // ---- W axis: keys at (c, h, y, d), no mask ----
    {
        float e[64];
#pragma unroll
        for (int y = 0; y < 64; ++y) {
            float a = 0.f;
#pragma unroll
            for (int c = 0; c < 8; ++c)
                a = fmaf(q[c], K[c * SQC + h * SH + y * SW + d], a);
            e[y] = a;
        }
        float mm = -INFINITY;
#pragma unroll
        for (int y = 0; y < 64; ++y) mm = fmaxf(mm, e[y]);
        float ll = 0.f;
#pragma unroll
        for (int y = 0; y < 64; ++y) ll += __expf(e[y] - mm);
        mW = mm; lW = ll;
    }
    __syncthreads();

    // ---- D axis: keys at (c, h, w, z), mask z==d ----
    {
        float e[64];
#pragma unroll
        for (int z = 0; z < 64; ++z) {
            float a = 0.f;
#pragma unroll
            for (int c = 0; c < 8; ++c)
                a = fmaf(q[c], K[c * SQC + h * SH + w * SW + z], a);
            e[z] = (z == d) ? -INFINITY : a;
        }
        float mm = -INFINITY;
#pragma unroll
        for (int z = 0; z < 64; ++z) mm = fmaxf(mm, e[z]);
        float ll = 0.f;
#pragma unroll
        for (int z = 0; z < 64; ++z) ll += __expf(e[z] - mm);
        mD = mm; lD = ll;
    }

    const float m = fmaxf(fmaxf(mH, mW), mD);
    const float l = lH * __expf(mH - m) + lW * __expf(mW - m) + lD * __expf(mD - m);
    const int idx = h * SH + w * SW + d;
    m_ws[idx]  = m;
    rl_ws[idx] = 1.0f / l;
}

// ---------------------------------------------------------------------------
// K2: D-axis pass. Block = (h,w), one wave. out[c][d] = sum_z V[c,h,w,z]*A[z][d].
// Writes out (first pass; d_out is poisoned before every launch).
// ---------------------------------------------------------------------------
__global__ __launch_bounds__(64) void k_dpass(
    const float* __restrict__ Q, const float* __restrict__ K, const float* __restrict__ V,
    const float* __restrict__ m_ws, const float* __restrict__ rl_ws,
    float* __restrict__ out)
{
    __shared__ float VDT[64][68];   // [z][c], +4 pad for staging writes
    __shared__ float AZ[64][64];    // [z][d]
    __shared__ float KD[8][64];     // [c][z]

    const int lane = threadIdx.x;                 // = d for energy role
    const int h = blockIdx.x >> 6, w = blockIdx.x & 63;
    const int base = h * SH + w * SW;

#pragma unroll
    for (int c = 0; c < 8; ++c) KD[c][lane] = K[c * SQC + base + lane];

    // stage V transposed: VDT[z=lane][c]
#pragma unroll
    for (int cq = 0; cq < 16; ++cq) {
        float4 v;
        v.x = V[(4 * cq + 0) * SQC + base + lane];
        v.y = V[(4 * cq + 1) * SQC + base + lane];
        v.z = V[(4 * cq + 2) * SQC + base + lane];
        v.w = V[(4 * cq + 3) * SQC + base + lane];
        *reinterpret_cast<float4*>(&VDT[lane][4 * cq]) = v;
    }

    float q[8];
#pragma unroll
    for (int c = 0; c < 8; ++c) q[c] = Q[c * SQC + base + lane];

    __syncthreads();

    // energies for query d=lane vs all z
    float e[64];
#pragma unroll
    for (int z = 0; z < 64; ++z) e[z] = 0.f;
#pragma unroll
    for (int c = 0; c < 8; ++c) {
#pragma unroll
        for (int zq = 0; zq < 16; ++zq) {
            const float4 k4 = *reinterpret_cast<const float4*>(&KD[c][4 * zq]);
            e[4 * zq + 0] = fmaf(q[c], k4.x, e[4 * zq + 0]);
            e[4 * zq + 1] = fmaf(q[c], k4.y, e[4 * zq + 1]);
            e[4 * zq + 2] = fmaf(q[c], k4.z, e[4 * zq + 2]);
            e[4 * zq + 3] = fmaf(q[c], k4.w, e[4 * zq + 3]);
        }
    }
    const int qidx = base + lane;
    const float m  = m_ws[qidx];
    const float rl = rl_ws[qidx];
#pragma unroll
    for (int z = 0; z < 64; ++z)
        AZ[z][lane] = (z == lane) ? 0.f : __expf(e[z] - m) * rl;

    __syncthreads();

    // 64x64x64 matmul, 8x8 per lane
    const int i = lane >> 3, j = lane & 7;
    float acc[8][8];
#pragma unroll
    for (int a = 0; a < 8; ++a)
#pragma unroll
        for (int b = 0; b < 8; ++b) acc[a][b] = 0.f;

#pragma unroll 4
    for (int z = 0; z < 64; ++z) {
        float va[8], vb[8];
        *reinterpret_cast<float4*>(&va[0]) = *reinterpret_cast<const float4*>(&VDT[z][8 * i]);
        *reinterpret_cast<float4*>(&va[4]) = *reinterpret_cast<const float4*>(&VDT[z][8 * i + 4]);
        *reinterpret_cast<float4*>(&vb[0]) = *reinterpret_cast<const float4*>(&AZ[z][8 * j]);
        *reinterpret_cast<float4*>(&vb[4]) = *reinterpret_cast<const float4*>(&AZ[z][8 * j + 4]);
#pragma unroll
        for (int a = 0; a < 8; ++a)
#pragma unroll
            for (int b = 0; b < 8; ++b)
                acc[a][b] = fmaf(va[a], vb[b], acc[a][b]);
    }

#pragma unroll
    for (int a = 0; a < 8; ++a) {
        const float4 o0 = make_float4(acc[a][0], acc[a][1], acc[a][2], acc[a][3]);
        const float4 o1 = make_float4(acc[a][4], acc[a][5], acc[a][6], acc[a][7]);
        float* op = &out[(8 * i + a) * SQC + base + 8 * j];
        *reinterpret_cast<float4*>(op)     = o0;
        *reinterpret_cast<float4*>(op + 4) = o1;
    }
}

// ---------------------------------------------------------------------------
// K3: H-axis pass. Block = (w, 16-h tile), 1024 thr. Streams x; V read once.
// out[c, hbase+ha, w, d] += sum_x V[c,x,w,d] * A_H[ha][d](x).
// ---------------------------------------------------------------------------
__global__ __launch_bounds__(1024, 4) void k_hpass(
    const float* __restrict__ Q, const float* __restrict__ K, const float* __restrict__ V,
    const float* __restrict__ m_ws, const float* __restrict__ rl_ws,
    float* __restrict__ out)
{
    __shared__ float Kx[8][64];
    __shared__ float Vx[64][64];
    __shared__ float Ax[16][64];

    const int tid = threadIdx.x;
    const int d   = tid & 63;
    const int g   = tid >> 6;                  // 0..15
    const int w     = blockIdx.x & 63;
    const int hbase = (blockIdx.x >> 6) << 4;  // 0,16,32,48

    // energy role: query (h_e, w, d)
    const int h_e = hbase + g;
    float q[8];
#pragma unroll
    for (int c = 0; c < 8; ++c) q[c] = Q[c * SQC + h_e * SH + w * SW + d];
    const int qidx = h_e * SH + w * SW + d;
    const float m = m_ws[qidx], rl = rl_ws[qidx];

    // MAC role: c-octet co, h-octet hh
    const int co = g & 7, hh = g >> 3;
    float acc[8][8];
#pragma unroll
    for (int a = 0; a < 8; ++a)
#pragma unroll
        for (int b = 0; b < 8; ++b) acc[a][b] = 0.f;

    for (int x = 0; x < 64; ++x) {
        if (tid < 512) Kx[tid >> 6][d] = K[(tid >> 6) * SQC + x * SH + w * SW + d];
#pragma unroll
        for (int r = 0; r < 4; ++r) {
            const int c = r * 16 + g;
            Vx[c][d] = V[c * SQC + x * SH + w * SW + d];
        }
        __syncthreads();

        float e = 0.f;
#pragma unroll
        for (int c = 0; c < 8; ++c) e = fmaf(q[c], Kx[c][d], e);
        Ax[g][d] = (x == h_e) ? 0.f : __expf(e - m) * rl;
        __syncthreads();

        float va[8], pa[8];
#pragma unroll
        for (int cc = 0; cc < 8; ++cc) va[cc] = Vx[8 * co + cc][d];
#pragma unroll
        for (int aa = 0; aa < 8; ++aa) pa[aa] = Ax[8 * hh + aa][d];
#pragma unroll
        for (int cc = 0; cc < 8; ++cc)
#pragma unroll
            for (int aa = 0; aa < 8; ++aa)
                acc[cc][aa] = fmaf(va[cc], pa[aa], acc[cc][aa]);
        __syncthreads();
    }

#pragma unroll
    for (int cc = 0; cc < 8; ++cc)
#pragma unroll
        for (int aa = 0; aa < 8; ++aa) {
            float* op = &out[(8 * co + cc) * SQC + (hbase + 8 * hh + aa) * SH + w * SW + d];
            *op += acc[cc][aa];
        }
}

// ---------------------------------------------------------------------------
// K4: W-axis pass. Block = (h, 16-w tile), 1024 thr. Streams y; no mask.
// out[c, h, wbase+wa, d] += sum_y V[c,h,y,d] * A_W[wa][d](y).
// ---------------------------------------------------------------------------
__global__ __launch_bounds__(1024, 4) void k_wpass(
    const float* __restrict__ Q, const float* __restrict__ K, const float* __restrict__ V,
    const float* __restrict__ m_ws, const float* __restrict__ rl_ws,
    float* __restrict__ out)
{
    __shared__ float Ky[8][64];
    __shared__ float Vy[64][64];
    __shared__ float Ay[16][64];

    const int tid = threadIdx.x;
    const int d   = tid & 63;
    const int g   = tid >> 6;
    const int h     = blockIdx.x & 63;
    const int wbase = (blockIdx.x >> 6) << 4;

    const int w_e = wbase + g;
    float q[8];
#pragma unroll
    for (int c = 0; c < 8; ++c) q[c] = Q[c * SQC + h * SH + w_e * SW + d];
    const int qidx = h * SH + w_e * SW + d;
    const float m = m_ws[qidx], rl = rl_ws[qidx];

    const int co = g & 7, wh = g >> 3;
    float acc[8][8];
#pragma unroll
    for (int a = 0; a < 8; ++a)
#pragma unroll
        for (int b = 0; b < 8; ++b) acc[a][b] = 0.f;

    for (int y = 0; y < 64; ++y) {
        if (tid < 512) Ky[tid >> 6][d] = K[(tid >> 6) * SQC + h * SH + y * SW + d];
#pragma unroll
        for (int r = 0; r < 4; ++r) {
            const int c = r * 16 + g;
            Vy[c][d] = V[c * SQC + h * SH + y * SW + d];
        }
        __syncthreads();

        float e = 0.f;
#pragma unroll
        for (int c = 0; c < 8; ++c) e = fmaf(q[c], Ky[c][d], e);
        Ay[g][d] = __expf(e - m) * rl;      // no diagonal mask on W
        __syncthreads();

        float va[8], pa[8];
#pragma unroll
        for (int cc = 0; cc < 8; ++cc) va[cc] = Vy[8 * co + cc][d];
#pragma unroll
        for (int ww = 0; ww < 8; ++ww) pa[ww] = Ay[8 * wh + ww][d];
#pragma unroll
        for (int cc = 0; cc < 8; ++cc)
#pragma unroll
            for (int ww = 0; ww < 8; ++ww)
                acc[cc][ww] = fmaf(va[cc], pa[ww], acc[cc][ww]);
        __syncthreads();
    }

#pragma unroll
    for (int cc = 0; cc < 8; ++cc)
#pragma unroll
        for (int ww = 0; ww < 8; ++ww) {
            float* op = &out[(8 * co + cc) * SQC + h * SH + (wbase + 8 * wh + ww) * SW + d];
            *op += acc[cc][ww];
        }
}

// ---------------------------------------------------------------------------
extern "C" void kernel_launch(void* const* d_in, const int* in_sizes, int n_in,
                              void* d_out, int out_size, void* d_ws, size_t ws_size,
                              hipStream_t stream)
{
    const float* Q = (const float*)d_in[0];
    const float* K = (const float*)d_in[1];
    const float* V = (const float*)d_in[2];
    float* out = (float*)d_out;

    float* m_ws  = (float*)d_ws;          // 262144 floats
    float* rl_ws = m_ws + SQC;            // 262144 floats (ws needs 2 MB)

    hipLaunchKernelGGL(k_stats, dim3(256),  dim3(1024), 0, stream, Q, K, m_ws, rl_ws);
    hipLaunchKernelGGL(k_dpass, dim3(4096), dim3(64),   0, stream, Q, K, V, m_ws, rl_ws, out);
    hipLaunchKernelGGL(k_hpass, dim3(256),  dim3(1024), 0, stream, Q, K, V, m_ws, rl_ws, out);
    hipLaunchKernelGGL(k_wpass, dim3(256),  dim3(1024), 0, stream, Q, K, V, m_ws, rl_ws, out);
}

// Round 3
// 571.915 us; speedup vs baseline: 1.4926x; 1.4926x over previous
//
#include <hip/hip_runtime.h>
#include <math.h>

// Problem constants: B=1, CQ=8, CV=64, H=W=D=64, fp32.
#define SQC 262144   // channel stride = 64*64*64
#define SH  4096     // h stride = 64*64
#define SW  64       // w stride

// ---------------------------------------------------------------------------
// K1: per-query softmax stats (m = max over 192 energies, rl = 1/sum(exp)).
// Block covers 4h x 4w, 16 waves; wave = one (h,w); lane = d.
// Chunked-online softmax: 8 energies in registers at a time -> no e[64] array,
// no scratch spill (round-0 version spilled ~550 MB of scratch to HBM).
// ---------------------------------------------------------------------------
__global__ __launch_bounds__(1024, 4) void k_stats(
    const float* __restrict__ Q, const float* __restrict__ K,
    float* __restrict__ m_ws, float* __restrict__ rl_ws)
{
    const int tid = threadIdx.x;
    const int d   = tid & 63;
    const int wid = tid >> 6;                 // 0..15
    const int hg = blockIdx.x >> 4, wg = blockIdx.x & 15;
    const int h = hg * 4 + (wid >> 2);
    const int w = wg * 4 + (wid & 3);

    float q[8];
#pragma unroll
    for (int c = 0; c < 8; ++c) q[c] = Q[c * SQC + h * SH + w * SW + d];

    float m = -INFINITY, l = 0.f;

    // ---- H axis: keys at (c, x, w, d), mask x==h (wave-uniform) ----
#pragma unroll 1
    for (int xc = 0; xc < 8; ++xc) {
        float e[8];
#pragma unroll
        for (int xi = 0; xi < 8; ++xi) {
            const int x = xc * 8 + xi;
            float a = 0.f;
#pragma unroll
            for (int c = 0; c < 8; ++c)
                a = fmaf(q[c], K[c * SQC + x * SH + w * SW + d], a);
            e[xi] = (x == h) ? -INFINITY : a;
        }
        float cm = e[0];
#pragma unroll
        for (int xi = 1; xi < 8; ++xi) cm = fmaxf(cm, e[xi]);
        const float nm = fmaxf(m, cm);
        float s = 0.f;
#pragma unroll
        for (int xi = 0; xi < 8; ++xi) s += __expf(e[xi] - nm);
        l = fmaf(l, __expf(m - nm), s);
        m = nm;
    }

    // ---- W axis: keys at (c, h, y, d), no mask ----
#pragma unroll 1
    for (int yc = 0; yc < 8; ++yc) {
        float e[8];
#pragma unroll
        for (int yi = 0; yi < 8; ++yi) {
            const int y = yc * 8 + yi;
            float a = 0.f;
#pragma unroll
            for (int c = 0; c < 8; ++c)
                a = fmaf(q[c], K[c * SQC + h * SH + y * SW + d], a);
            e[yi] = a;
        }
        float cm = e[0];
#pragma unroll
        for (int yi = 1; yi < 8; ++yi) cm = fmaxf(cm, e[yi]);
        const float nm = fmaxf(m, cm);
        float s = 0.f;
#pragma unroll
        for (int yi = 0; yi < 8; ++yi) s += __expf(e[yi] - nm);
        l = fmaf(l, __expf(m - nm), s);
        m = nm;
    }

    // ---- D axis: keys at (c, h, w, z), mask z==d (per-lane, via -inf) ----
#pragma unroll 1
    for (int zc = 0; zc < 8; ++zc) {
        float e[8];
#pragma unroll
        for (int zi = 0; zi < 8; ++zi) {
            const int z = zc * 8 + zi;
            float a = 0.f;
#pragma unroll
            for (int c = 0; c < 8; ++c)
                a = fmaf(q[c], K[c * SQC + h * SH + w * SW + z], a);
            e[zi] = (z == d) ? -INFINITY : a;
        }
        float cm = e[0];
#pragma unroll
        for (int zi = 1; zi < 8; ++zi) cm = fmaxf(cm, e[zi]);
        const float nm = fmaxf(m, cm);
        float s = 0.f;
#pragma unroll
        for (int zi = 0; zi < 8; ++zi) s += __expf(e[zi] - nm);
        l = fmaf(l, __expf(m - nm), s);
        m = nm;
    }

    const int idx = h * SH + w * SW + d;
    m_ws[idx]  = m;
    rl_ws[idx] = 1.0f / l;
}

// ---------------------------------------------------------------------------
// K2: D-axis pass. Block = (h,w), one wave. out[c][d] = sum_z V[c,h,w,z]*A[z][d].
// Writes out (first pass; d_out is poisoned before every launch).
// ---------------------------------------------------------------------------
__global__ __launch_bounds__(64) void k_dpass(
    const float* __restrict__ Q, const float* __restrict__ K, const float* __restrict__ V,
    const float* __restrict__ m_ws, const float* __restrict__ rl_ws,
    float* __restrict__ out)
{
    __shared__ float VDT[64][68];   // [z][c], +4 pad for staging writes
    __shared__ float AZ[64][64];    // [z][d]
    __shared__ float KD[8][64];     // [c][z]

    const int lane = threadIdx.x;                 // = d for energy role
    const int h = blockIdx.x >> 6, w = blockIdx.x & 63;
    const int base = h * SH + w * SW;

#pragma unroll
    for (int c = 0; c < 8; ++c) KD[c][lane] = K[c * SQC + base + lane];

    // stage V transposed: VDT[z=lane][c]
#pragma unroll
    for (int cq = 0; cq < 16; ++cq) {
        float4 v;
        v.x = V[(4 * cq + 0) * SQC + base + lane];
        v.y = V[(4 * cq + 1) * SQC + base + lane];
        v.z = V[(4 * cq + 2) * SQC + base + lane];
        v.w = V[(4 * cq + 3) * SQC + base + lane];
        *reinterpret_cast<float4*>(&VDT[lane][4 * cq]) = v;
    }

    float q[8];
#pragma unroll
    for (int c = 0; c < 8; ++c) q[c] = Q[c * SQC + base + lane];

    __syncthreads();

    // energies for query d=lane vs all z
    float e[64];
#pragma unroll
    for (int z = 0; z < 64; ++z) e[z] = 0.f;
#pragma unroll
    for (int c = 0; c < 8; ++c) {
#pragma unroll
        for (int zq = 0; zq < 16; ++zq) {
            const float4 k4 = *reinterpret_cast<const float4*>(&KD[c][4 * zq]);
            e[4 * zq + 0] = fmaf(q[c], k4.x, e[4 * zq + 0]);
            e[4 * zq + 1] = fmaf(q[c], k4.y, e[4 * zq + 1]);
            e[4 * zq + 2] = fmaf(q[c], k4.z, e[4 * zq + 2]);
            e[4 * zq + 3] = fmaf(q[c], k4.w, e[4 * zq + 3]);
        }
    }
    const int qidx = base + lane;
    const float m  = m_ws[qidx];
    const float rl = rl_ws[qidx];
#pragma unroll
    for (int z = 0; z < 64; ++z)
        AZ[z][lane] = (z == lane) ? 0.f : __expf(e[z] - m) * rl;

    __syncthreads();

    // 64x64x64 matmul, 8x8 per lane
    const int i = lane >> 3, j = lane & 7;
    float acc[8][8];
#pragma unroll
    for (int a = 0; a < 8; ++a)
#pragma unroll
        for (int b = 0; b < 8; ++b) acc[a][b] = 0.f;

#pragma unroll 4
    for (int z = 0; z < 64; ++z) {
        float va[8], vb[8];
        *reinterpret_cast<float4*>(&va[0]) = *reinterpret_cast<const float4*>(&VDT[z][8 * i]);
        *reinterpret_cast<float4*>(&va[4]) = *reinterpret_cast<const float4*>(&VDT[z][8 * i + 4]);
        *reinterpret_cast<float4*>(&vb[0]) = *reinterpret_cast<const float4*>(&AZ[z][8 * j]);
        *reinterpret_cast<float4*>(&vb[4]) = *reinterpret_cast<const float4*>(&AZ[z][8 * j + 4]);
#pragma unroll
        for (int a = 0; a < 8; ++a)
#pragma unroll
            for (int b = 0; b < 8; ++b)
                acc[a][b] = fmaf(va[a], vb[b], acc[a][b]);
    }

#pragma unroll
    for (int a = 0; a < 8; ++a) {
        const float4 o0 = make_float4(acc[a][0], acc[a][1], acc[a][2], acc[a][3]);
        const float4 o1 = make_float4(acc[a][4], acc[a][5], acc[a][6], acc[a][7]);
        float* op = &out[(8 * i + a) * SQC + base + 8 * j];
        *reinterpret_cast<float4*>(op)     = o0;
        *reinterpret_cast<float4*>(op + 4) = o1;
    }
}

// ---------------------------------------------------------------------------
// K3: H-axis pass. Block = (w, 16-h tile), 1024 thr. Streams x; V read once.
// out[c, hbase+ha, w, d] += sum_x V[c,x,w,d] * A_H[ha][d](x).
// ---------------------------------------------------------------------------
__global__ __launch_bounds__(1024, 4) void k_hpass(
    const float* __restrict__ Q, const float* __restrict__ K, const float* __restrict__ V,
    const float* __restrict__ m_ws, const float* __restrict__ rl_ws,
    float* __restrict__ out)
{
    __shared__ float Kx[8][64];
    __shared__ float Vx[64][64];
    __shared__ float Ax[16][64];

    const int tid = threadIdx.x;
    const int d   = tid & 63;
    const int g   = tid >> 6;                  // 0..15
    const int w     = blockIdx.x & 63;
    const int hbase = (blockIdx.x >> 6) << 4;  // 0,16,32,48

    // energy role: query (h_e, w, d)
    const int h_e = hbase + g;
    float q[8];
#pragma unroll
    for (int c = 0; c < 8; ++c) q[c] = Q[c * SQC + h_e * SH + w * SW + d];
    const int qidx = h_e * SH + w * SW + d;
    const float m = m_ws[qidx], rl = rl_ws[qidx];

    // MAC role: c-octet co, h-octet hh
    const int co = g & 7, hh = g >> 3;
    float acc[8][8];
#pragma unroll
    for (int a = 0; a < 8; ++a)
#pragma unroll
        for (int b = 0; b < 8; ++b) acc[a][b] = 0.f;

    for (int x = 0; x < 64; ++x) {
        if (tid < 512) Kx[tid >> 6][d] = K[(tid >> 6) * SQC + x * SH + w * SW + d];
#pragma unroll
        for (int r = 0; r < 4; ++r) {
            const int c = r * 16 + g;
            Vx[c][d] = V[c * SQC + x * SH + w * SW + d];
        }
        __syncthreads();

        float e = 0.f;
#pragma unroll
        for (int c = 0; c < 8; ++c) e = fmaf(q[c], Kx[c][d], e);
        Ax[g][d] = (x == h_e) ? 0.f : __expf(e - m) * rl;
        __syncthreads();

        float va[8], pa[8];
#pragma unroll
        for (int cc = 0; cc < 8; ++cc) va[cc] = Vx[8 * co + cc][d];
#pragma unroll
        for (int aa = 0; aa < 8; ++aa) pa[aa] = Ax[8 * hh + aa][d];
#pragma unroll
        for (int cc = 0; cc < 8; ++cc)
#pragma unroll
            for (int aa = 0; aa < 8; ++aa)
                acc[cc][aa] = fmaf(va[cc], pa[aa], acc[cc][aa]);
        __syncthreads();
    }

#pragma unroll
    for (int cc = 0; cc < 8; ++cc)
#pragma unroll
        for (int aa = 0; aa < 8; ++aa) {
            float* op = &out[(8 * co + cc) * SQC + (hbase + 8 * hh + aa) * SH + w * SW + d];
            *op += acc[cc][aa];
        }
}

// ---------------------------------------------------------------------------
// K4: W-axis pass. Block = (h, 16-w tile), 1024 thr. Streams y; no mask.
// out[c, h, wbase+wa, d] += sum_y V[c,h,y,d] * A_W[wa][d](y).
// ---------------------------------------------------------------------------
__global__ __launch_bounds__(1024, 4) void k_wpass(
    const float* __restrict__ Q, const float* __restrict__ K, const float* __restrict__ V,
    const float* __restrict__ m_ws, const float* __restrict__ rl_ws,
    float* __restrict__ out)
{
    __shared__ float Ky[8][64];
    __shared__ float Vy[64][64];
    __shared__ float Ay[16][64];

    const int tid = threadIdx.x;
    const int d   = tid & 63;
    const int g   = tid >> 6;
    const int h     = blockIdx.x & 63;
    const int wbase = (blockIdx.x >> 6) << 4;

    const int w_e = wbase + g;
    float q[8];
#pragma unroll
    for (int c = 0; c < 8; ++c) q[c] = Q[c * SQC + h * SH + w_e * SW + d];
    const int qidx = h * SH + w_e * SW + d;
    const float m = m_ws[qidx], rl = rl_ws[qidx];

    const int co = g & 7, wh = g >> 3;
    float acc[8][8];
#pragma unroll
    for (int a = 0; a < 8; ++a)
#pragma unroll
        for (int b = 0; b < 8; ++b) acc[a][b] = 0.f;

    for (int y = 0; y < 64; ++y) {
        if (tid < 512) Ky[tid >> 6][d] = K[(tid >> 6) * SQC + h * SH + y * SW + d];
#pragma unroll
        for (int r = 0; r < 4; ++r) {
            const int c = r * 16 + g;
            Vy[c][d] = V[c * SQC + h * SH + y * SW + d];
        }
        __syncthreads();

        float e = 0.f;
#pragma unroll
        for (int c = 0; c < 8; ++c) e = fmaf(q[c], Ky[c][d], e);
        Ay[g][d] = __expf(e - m) * rl;      // no diagonal mask on W
        __syncthreads();

        float va[8], pa[8];
#pragma unroll
        for (int cc = 0; cc < 8; ++cc) va[cc] = Vy[8 * co + cc][d];
#pragma unroll
        for (int ww = 0; ww < 8; ++ww) pa[ww] = Ay[8 * wh + ww][d];
#pragma unroll
        for (int cc = 0; cc < 8; ++cc)
#pragma unroll
            for (int ww = 0; ww < 8; ++ww)
                acc[cc][ww] = fmaf(va[cc], pa[ww], acc[cc][ww]);
        __syncthreads();
    }

#pragma unroll
    for (int cc = 0; cc < 8; ++cc)
#pragma unroll
        for (int ww = 0; ww < 8; ++ww) {
            float* op = &out[(8 * co + cc) * SQC + h * SH + (wbase + 8 * wh + ww) * SW + d];
            *op += acc[cc][ww];
        }
}

// ---------------------------------------------------------------------------
extern "C" void kernel_launch(void* const* d_in, const int* in_sizes, int n_in,
                              void* d_out, int out_size, void* d_ws, size_t ws_size,
                              hipStream_t stream)
{
    const float* Q = (const float*)d_in[0];
    const float* K = (const float*)d_in[1];
    const float* V = (const float*)d_in[2];
    float* out = (float*)d_out;

    float* m_ws  = (float*)d_ws;          // 262144 floats
    float* rl_ws = m_ws + SQC;            // 262144 floats (ws needs 2 MB)

    hipLaunchKernelGGL(k_stats, dim3(256),  dim3(1024), 0, stream, Q, K, m_ws, rl_ws);
    hipLaunchKernelGGL(k_dpass, dim3(4096), dim3(64),   0, stream, Q, K, V, m_ws, rl_ws, out);
    hipLaunchKernelGGL(k_hpass, dim3(256),  dim3(1024), 0, stream, Q, K, V, m_ws, rl_ws, out);
    hipLaunchKernelGGL(k_wpass, dim3(256),  dim3(1024), 0, stream, Q, K, V, m_ws, rl_ws, out);
}